// Round 1
// baseline (4244.558 us; speedup 1.0000x reference)
//
#include <hip/hip_runtime.h>
#include <cmath>

// Problem constants (from reference): V=50000, E=300, H=512, L=6, N=8192, K=4
#define EDIM 300
#define HDIM 512
#define LVLS 6
#define NN   8192
#define KCH  4

// GEMM tile
#define BM 64
#define BN 64
#define BK 16
#define AKPAD 20   // LDS A row stride (floats): keeps float4 alignment, no pow2 bank stride

__device__ __forceinline__ float sigf(float x) { return 1.0f / (1.0f + expf(-x)); }

// MODEA: 0 = A is dense row-major [M,Kd]
//        1 = A row r = Asrc[aidx[r]] * amask[r]  (gather + mask)
// EPI:   0 = C  = acc
//        1 = C  = acc + bias[col]
//        2 = C += acc
//        3 = forget-gate epilogue: thread's 4 rows are the 4 children of one node;
//            fc[node,col] = sum_k sigmoid(acc + xWf[node,col] + bf[col]) * cmask * c_old[cidx,col]
template <int MODEA, int EPI>
__global__ __launch_bounds__(256) void gemm_k(
    const float* __restrict__ Asrc, const int* __restrict__ aidx, const float* __restrict__ amask,
    const float* __restrict__ B, const float* __restrict__ bias,
    float* __restrict__ C,
    const float* __restrict__ xWf, const float* __restrict__ bf,
    const int* __restrict__ cidx, const float* __restrict__ cmask,
    const float* __restrict__ c_old,
    int M, int Kd, int Nd)
{
    __shared__ float As[BM][AKPAD];
    __shared__ float Bs[BK][BN];

    const int tid = threadIdx.x;
    const int tx = tid & 15;        // 16 col-threads
    const int ty = tid >> 4;        // 16 row-threads
    const int tile_m = blockIdx.y * BM;
    const int tile_n = blockIdx.x * BN;
    const int row0 = tile_m + ty * 4;   // 4 contiguous rows per thread (EPI==3 needs this)
    const int col0 = tile_n + tx * 4;

    float acc[4][4] = {};

    for (int k0 = 0; k0 < Kd; k0 += BK) {
        // ---- load A tile: 64x16, coalesced 16 consecutive cols per row ----
#pragma unroll
        for (int j = 0; j < 4; ++j) {
            int i  = tid + 256 * j;
            int ar = i >> 4;        // 0..63
            int ac = i & 15;        // 0..15
            int gk = k0 + ac;
            float v = 0.0f;
            if (gk < Kd) {
                if (MODEA == 0) {
                    v = Asrc[(size_t)(tile_m + ar) * Kd + gk];
                } else {
                    int src = aidx[tile_m + ar];
                    v = Asrc[(size_t)src * Kd + gk] * amask[tile_m + ar];
                }
            }
            As[ar][ac] = v;
        }
        // ---- load B tile: 16x64, coalesced ----
#pragma unroll
        for (int j = 0; j < 4; ++j) {
            int i  = tid + 256 * j;
            int br = i >> 6;        // 0..15
            int bc = i & 63;        // 0..63
            int gk = k0 + br;
            Bs[br][bc] = (gk < Kd) ? B[(size_t)gk * Nd + tile_n + bc] : 0.0f;
        }
        __syncthreads();

        // ---- 4x4 micro-tile FMA, float4 LDS reads ----
#pragma unroll
        for (int kk = 0; kk < BK; kk += 4) {
            float4 a4[4], b4[4];
#pragma unroll
            for (int i2 = 0; i2 < 4; ++i2) a4[i2] = *(const float4*)&As[ty * 4 + i2][kk];
#pragma unroll
            for (int d = 0; d < 4; ++d)    b4[d]  = *(const float4*)&Bs[kk + d][tx * 4];
#pragma unroll
            for (int i2 = 0; i2 < 4; ++i2) {
                const float av[4] = {a4[i2].x, a4[i2].y, a4[i2].z, a4[i2].w};
#pragma unroll
                for (int d = 0; d < 4; ++d) {
                    acc[i2][0] += av[d] * b4[d].x;
                    acc[i2][1] += av[d] * b4[d].y;
                    acc[i2][2] += av[d] * b4[d].z;
                    acc[i2][3] += av[d] * b4[d].w;
                }
            }
        }
        __syncthreads();
    }

    if (EPI == 3) {
        // rows row0..row0+3 are children k=0..3 of node = row0/4 (BM%4==0 guarantees this)
        const int node = row0 >> 2;
        float xw[4], bv[4], outv[4] = {0, 0, 0, 0};
#pragma unroll
        for (int j = 0; j < 4; ++j) {
            xw[j] = xWf[(size_t)node * HDIM + col0 + j];
            bv[j] = bf[col0 + j];
        }
#pragma unroll
        for (int i2 = 0; i2 < 4; ++i2) {
            int r = row0 + i2;
            int ch = cidx[r];
            float m = cmask[r];
            const float* crow = c_old + (size_t)ch * HDIM + col0;
#pragma unroll
            for (int j = 0; j < 4; ++j) {
                float f = sigf(acc[i2][j] + xw[j] + bv[j]);
                outv[j] += f * m * crow[j];
            }
        }
#pragma unroll
        for (int j = 0; j < 4; ++j) C[(size_t)node * HDIM + col0 + j] = outv[j];
    } else {
#pragma unroll
        for (int i2 = 0; i2 < 4; ++i2) {
            size_t base = (size_t)(row0 + i2) * Nd + col0;
#pragma unroll
            for (int j = 0; j < 4; ++j) {
                float v = acc[i2][j];
                if (EPI == 1) v += bias[col0 + j];
                if (EPI == 2) C[base + j] += v;
                else          C[base + j] = v;
            }
        }
    }
}

// h_tilde[n,:] = sum_k cmask[n,k] * h_prev[cidx[n,k], :]
__global__ __launch_bounds__(256) void htilde_k(
    const float* __restrict__ h, const int* __restrict__ cidx,
    const float* __restrict__ cmask, float* __restrict__ outp)
{
    int t  = blockIdx.x * 256 + threadIdx.x;   // NN*HDIM/4 threads
    int n  = t >> 7;                           // HDIM/4 = 128 threads per node
    int j4 = (t & 127) << 2;
    float4 s = make_float4(0, 0, 0, 0);
#pragma unroll
    for (int k = 0; k < KCH; ++k) {
        int ch  = cidx[n * KCH + k];
        float m = cmask[n * KCH + k];
        float4 v = *(const float4*)(h + (size_t)ch * HDIM + j4);
        s.x += m * v.x; s.y += m * v.y; s.z += m * v.z; s.w += m * v.w;
    }
    *(float4*)(outp + (size_t)n * HDIM + j4) = s;
}

// c = sigmoid(i)*tanh(u) + fc ; h = sigmoid(o)*tanh(c)
template <bool LEAF>
__global__ __launch_bounds__(256) void gate_k(
    const float* __restrict__ iou, const float* __restrict__ fc,
    float* __restrict__ c_new, float* __restrict__ h_new)
{
    int t  = blockIdx.x * 256 + threadIdx.x;   // NN*HDIM/4 threads
    int n  = t >> 7;
    int j4 = (t & 127) << 2;
    const float* base = iou + (size_t)n * 3 * HDIM;
    float4 iv = *(const float4*)(base + j4);
    float4 ov = *(const float4*)(base + HDIM + j4);
    float4 uv = *(const float4*)(base + 2 * HDIM + j4);
    float4 fcv = LEAF ? make_float4(0, 0, 0, 0)
                      : *(const float4*)(fc + (size_t)n * HDIM + j4);
    float4 cv, hv;
    cv.x = sigf(iv.x) * tanhf(uv.x) + fcv.x;
    cv.y = sigf(iv.y) * tanhf(uv.y) + fcv.y;
    cv.z = sigf(iv.z) * tanhf(uv.z) + fcv.z;
    cv.w = sigf(iv.w) * tanhf(uv.w) + fcv.w;
    hv.x = sigf(ov.x) * tanhf(cv.x);
    hv.y = sigf(ov.y) * tanhf(cv.y);
    hv.z = sigf(ov.z) * tanhf(cv.z);
    hv.w = sigf(ov.w) * tanhf(cv.w);
    *(float4*)(c_new + (size_t)n * HDIM + j4) = cv;
    *(float4*)(h_new + (size_t)n * HDIM + j4) = hv;
}

extern "C" void kernel_launch(void* const* d_in, const int* in_sizes, int n_in,
                              void* d_out, int out_size, void* d_ws, size_t ws_size,
                              hipStream_t stream)
{
    const int*   vocab_ix   = (const int*)d_in[0];     // [L,N]
    const int*   child_idx  = (const int*)d_in[1];     // [L,N,K]
    const float* token_mask = (const float*)d_in[2];   // [L,N]
    const float* child_mask = (const float*)d_in[3];   // [L,N,K]
    const float* embed      = (const float*)d_in[4];   // [V,E]
    const float* W_iou      = (const float*)d_in[5];   // [E,3H]
    const float* U_iou      = (const float*)d_in[6];   // [H,3H]
    const float* b_iou      = (const float*)d_in[7];   // [3H]
    const float* W_f        = (const float*)d_in[8];   // [E,H]
    const float* U_f        = (const float*)d_in[9];   // [H,H]
    const float* b_f        = (const float*)d_in[10];  // [H]
    float* out = (float*)d_out;                        // [N,H] (root level h)

    // Workspace layout (floats). Total = N*3H + 6*N*H = 37.75M floats ≈ 151 MB.
    float* ws  = (float*)d_ws;
    float* iou = ws;                                   // [N,3H]
    float* xwf = iou + (size_t)NN * 3 * HDIM;          // [N,H]
    float* htl = xwf + (size_t)NN * HDIM;              // [N,H]
    float* fc  = htl + (size_t)NN * HDIM;              // [N,H]
    float* h0  = fc  + (size_t)NN * HDIM;              // [N,H]
    float* c0  = h0  + (size_t)NN * HDIM;              // [N,H]
    float* c1  = c0  + (size_t)NN * HDIM;              // [N,H]

    // h double-buffer: parity over 6 levels lands level-0 h in d_out.
    float* hbuf[2] = { h0, out };
    float* cbuf[2] = { c0, c1 };

    dim3 blk(256);
    const int ew_blocks = NN * HDIM / 4 / 256;         // 4096

    for (int l = LVLS - 1; l >= 0; --l) {
        const int t = (LVLS - 1 - l) & 1;
        float* h_new  = hbuf[t];
        float* c_new  = cbuf[t];
        float* h_prev = hbuf[t ^ 1];
        float* c_prev = cbuf[t ^ 1];
        const int*   vix = vocab_ix   + (size_t)l * NN;
        const float* tm  = token_mask + (size_t)l * NN;
        const int*   cix = child_idx  + (size_t)l * NN * KCH;
        const float* cm  = child_mask + (size_t)l * NN * KCH;
        const bool leaf = (l == LVLS - 1);

        // iou = (embed[vix]*tm) @ W_iou + b_iou     [8192 x 300 x 1536]
        gemm_k<1, 1><<<dim3(3 * HDIM / BN, NN / BM), blk, 0, stream>>>(
            embed, vix, tm, W_iou, b_iou, iou,
            nullptr, nullptr, nullptr, nullptr, nullptr,
            NN, EDIM, 3 * HDIM);

        if (!leaf) {
            // xwf = (embed[vix]*tm) @ W_f           [8192 x 300 x 512]
            gemm_k<1, 0><<<dim3(HDIM / BN, NN / BM), blk, 0, stream>>>(
                embed, vix, tm, W_f, nullptr, xwf,
                nullptr, nullptr, nullptr, nullptr, nullptr,
                NN, EDIM, HDIM);

            // h_tilde = sum_k mask * h_prev[cidx]
            htilde_k<<<dim3(ew_blocks), blk, 0, stream>>>(h_prev, cix, cm, htl);

            // iou += h_tilde @ U_iou                [8192 x 512 x 1536]
            gemm_k<0, 2><<<dim3(3 * HDIM / BN, NN / BM), blk, 0, stream>>>(
                htl, nullptr, nullptr, U_iou, nullptr, iou,
                nullptr, nullptr, nullptr, nullptr, nullptr,
                NN, HDIM, 3 * HDIM);

            // fc = sum_k sigmoid((mask*h_prev[cidx]) @ U_f + xwf + b_f) * mask * c_prev[cidx]
            //                                       [32768 x 512 x 512] + fused epilogue
            gemm_k<1, 3><<<dim3(HDIM / BN, NN * KCH / BM), blk, 0, stream>>>(
                h_prev, cix, cm, U_f, nullptr, fc,
                xwf, b_f, cix, cm, c_prev,
                NN * KCH, HDIM, HDIM);

            gate_k<false><<<dim3(ew_blocks), blk, 0, stream>>>(iou, fc, c_new, h_new);
        } else {
            // leaf: h_tilde = 0, fc = 0
            gate_k<true><<<dim3(ew_blocks), blk, 0, stream>>>(iou, nullptr, c_new, h_new);
        }
    }
}

// Round 2
// 1014.549 us; speedup vs baseline: 4.1837x; 4.1837x over previous
//
#include <hip/hip_runtime.h>
#include <cmath>

// Problem constants: V=50000, E=300, H=512, L=6, N=8192, K=4
#define EDIM 300
#define EPAD 320      // E padded to multiple of 32 for bf16 MFMA K-loop
#define HDIM 512
#define LVLS 6
#define NN   8192
#define KCH  4

// MFMA GEMM tile: 128x128 block, BK=32, 4 waves of 64x64 (4x4 grid of 16x16x32 MFMA)
#define BM 128
#define BN 128
#define BK 32
#define LDSPAD 40     // LDS row stride in bf16 elems: 80 B = 5*16 B (aligned b128, non-pow2 banks)

typedef __attribute__((ext_vector_type(8))) short     bf16x8;
typedef __attribute__((ext_vector_type(8))) unsigned short us8;
typedef __attribute__((ext_vector_type(4))) unsigned short us4;
typedef __attribute__((ext_vector_type(4))) float     f32x4;

__device__ __forceinline__ float sigf(float x) { return 1.0f / (1.0f + expf(-x)); }

__device__ __forceinline__ unsigned short f2bf(float f) {
    unsigned u = __float_as_uint(f);
    u += 0x7FFF + ((u >> 16) & 1);           // RNE
    return (unsigned short)(u >> 16);
}
__device__ __forceinline__ float bf2f(unsigned short h) {
    return __uint_as_float(((unsigned)h) << 16);
}

// Transpose + convert weights: out[n][k] = bf16(in[k][n]), zero for k >= Kreal.
__global__ __launch_bounds__(256) void wconv_k(
    const float* __restrict__ in, unsigned short* __restrict__ out,
    int Kreal, int Ksp, int Nd)
{
    int t = blockIdx.x * 256 + threadIdx.x;   // total Nd*Ksp, k fast (coalesced writes)
    int k = t % Ksp;
    int n = t / Ksp;
    out[t] = (k < Kreal) ? f2bf(in[(size_t)k * Nd + n]) : (unsigned short)0;
}

// MODEA: 0 = dense A rows, 1 = gathered A rows (aidx) scaled by amask
// AF32 : 1 = A source is fp32 (row stride KrealA, bounds-checked), 0 = bf16 (row stride Ks)
// EPI  : 0 = C = acc ; 1 = C = acc + bias[col] ; 2 = C += acc ;
//        3 = fc epilogue: lane rows quad*4+reg are the 4 children of node rb>>2:
//            fc[node,col] = sum_r sigmoid(acc_r + xWf[node,col] + bf[col]) * cmask_r * c_old[cidx_r,col]
template <int MODEA, int AF32, int EPI>
__global__ __launch_bounds__(256) void mgemm_k(
    const float* __restrict__ Af, const unsigned short* __restrict__ Ab,
    const int* __restrict__ aidx, const float* __restrict__ amask,
    const unsigned short* __restrict__ Bt,   // [Nd][Ks] bf16 (transposed weights)
    const float* __restrict__ bias,
    float* __restrict__ C,
    const float* __restrict__ xwf, const float* __restrict__ bf_,
    const int* __restrict__ cidx, const float* __restrict__ cmask,
    const float* __restrict__ c_old,
    int M, int Ks, int KrealA, int Nd)
{
    __shared__ __align__(16) unsigned short As[BM][LDSPAD];
    __shared__ __align__(16) unsigned short Bs[BN][LDSPAD];

    const int tid    = threadIdx.x;
    const int tile_m = blockIdx.y * BM;
    const int tile_n = blockIdx.x * BN;

    // staging assignment: thread -> (row, half) ; 16 elems per thread per tile
    const int srow  = tid >> 1;          // 0..127
    const int skoff = (tid & 1) * 16;    // 0 or 16

    // hoisted A row source + mask
    int   asrc_row;
    float am = 1.0f;
    if (MODEA == 1) {
        asrc_row = aidx[tile_m + srow];
        am       = amask[tile_m + srow];
    } else {
        asrc_row = tile_m + srow;
    }
    const int brow = tile_n + srow;

    const int wave = tid >> 6;
    const int lane = tid & 63;
    const int wm   = (wave >> 1) * 64;
    const int wn   = (wave & 1) * 64;
    const int quad = lane >> 4;
    const int mcol = lane & 15;

    f32x4 acc[4][4] = {};

    for (int k0 = 0; k0 < Ks; k0 += BK) {
        // ---- stage A ----
        if (AF32) {
            const float* sp = Af + (size_t)asrc_row * KrealA + k0 + skoff;
            bf16x8 o0, o1;
#pragma unroll
            for (int g = 0; g < 4; ++g) {
                int kg = k0 + skoff + g * 4;
                float4 v = make_float4(0.f, 0.f, 0.f, 0.f);
                if (kg < KrealA) v = *(const float4*)(sp + g * 4);   // KrealA % 4 == 0
                unsigned short b0 = f2bf(v.x * am), b1 = f2bf(v.y * am);
                unsigned short b2 = f2bf(v.z * am), b3 = f2bf(v.w * am);
                if (g < 2) {
                    o0[g * 4 + 0] = (short)b0; o0[g * 4 + 1] = (short)b1;
                    o0[g * 4 + 2] = (short)b2; o0[g * 4 + 3] = (short)b3;
                } else {
                    o1[(g - 2) * 4 + 0] = (short)b0; o1[(g - 2) * 4 + 1] = (short)b1;
                    o1[(g - 2) * 4 + 2] = (short)b2; o1[(g - 2) * 4 + 3] = (short)b3;
                }
            }
            *(bf16x8*)&As[srow][skoff]     = o0;
            *(bf16x8*)&As[srow][skoff + 8] = o1;
        } else {
            const unsigned short* sp = Ab + (size_t)asrc_row * Ks + k0 + skoff;
            bf16x8 v0 = *(const bf16x8*)sp;
            bf16x8 v1 = *(const bf16x8*)(sp + 8);
            if (MODEA == 1) {
                if (am == 0.0f) {
                    v0 = (bf16x8)(short)0; v1 = (bf16x8)(short)0;
                } else if (am != 1.0f) {
#pragma unroll
                    for (int j = 0; j < 8; ++j) {
                        v0[j] = (short)f2bf(bf2f((unsigned short)v0[j]) * am);
                        v1[j] = (short)f2bf(bf2f((unsigned short)v1[j]) * am);
                    }
                }
            }
            *(bf16x8*)&As[srow][skoff]     = v0;
            *(bf16x8*)&As[srow][skoff + 8] = v1;
        }
        // ---- stage B (always bf16, padded rows are zero) ----
        {
            const unsigned short* sp = Bt + (size_t)brow * Ks + k0 + skoff;
            *(bf16x8*)&Bs[srow][skoff]     = *(const bf16x8*)sp;
            *(bf16x8*)&Bs[srow][skoff + 8] = *(const bf16x8*)(sp + 8);
        }
        __syncthreads();

        // ---- fragments + MFMA ----
        bf16x8 afr[4], bfr[4];
#pragma unroll
        for (int mt = 0; mt < 4; ++mt)
            afr[mt] = *(const bf16x8*)&As[wm + mt * 16 + mcol][quad * 8];
#pragma unroll
        for (int nt = 0; nt < 4; ++nt)
            bfr[nt] = *(const bf16x8*)&Bs[wn + nt * 16 + mcol][quad * 8];
#pragma unroll
        for (int mt = 0; mt < 4; ++mt)
#pragma unroll
            for (int nt = 0; nt < 4; ++nt)
                acc[mt][nt] = __builtin_amdgcn_mfma_f32_16x16x32_bf16(
                    afr[mt], bfr[nt], acc[mt][nt], 0, 0, 0);
        __syncthreads();
    }

    // ---- epilogue ----
    const int rbase = tile_m + wm;
    const int cbase = tile_n + wn;
    if (EPI == 3) {
#pragma unroll
        for (int mt = 0; mt < 4; ++mt) {
            const int rb   = rbase + mt * 16 + quad * 4;   // multiple of 4
            const int node = rb >> 2;
            const float4 cm = *(const float4*)&cmask[rb];
            const int4   ci = *(const int4*)&cidx[rb];
#pragma unroll
            for (int nt = 0; nt < 4; ++nt) {
                const int col = cbase + nt * 16 + mcol;
                const float xwb = xwf[(size_t)node * HDIM + col] + bf_[col];
                float s = 0.0f;
                s += sigf(acc[mt][nt][0] + xwb) * cm.x * c_old[(size_t)ci.x * HDIM + col];
                s += sigf(acc[mt][nt][1] + xwb) * cm.y * c_old[(size_t)ci.y * HDIM + col];
                s += sigf(acc[mt][nt][2] + xwb) * cm.z * c_old[(size_t)ci.z * HDIM + col];
                s += sigf(acc[mt][nt][3] + xwb) * cm.w * c_old[(size_t)ci.w * HDIM + col];
                C[(size_t)node * HDIM + col] = s;
            }
        }
    } else {
#pragma unroll
        for (int mt = 0; mt < 4; ++mt) {
#pragma unroll
            for (int nt = 0; nt < 4; ++nt) {
                const int col = cbase + nt * 16 + mcol;
                const float bv = (EPI == 1) ? bias[col] : 0.0f;
#pragma unroll
                for (int r = 0; r < 4; ++r) {
                    const int row = rbase + mt * 16 + quad * 4 + r;
                    size_t o = (size_t)row * Nd + col;
                    float v = acc[mt][nt][r] + bv;
                    if (EPI == 2) C[o] += v;
                    else          C[o] = v;
                }
            }
        }
    }
}

// h_tilde (bf16) = sum_k cmask * h_prev_bf16[cidx]
__global__ __launch_bounds__(256) void htilde_k(
    const unsigned short* __restrict__ hb, const int* __restrict__ cidx,
    const float* __restrict__ cmask, unsigned short* __restrict__ outp)
{
    int t  = blockIdx.x * 256 + threadIdx.x;   // NN*HDIM/8 threads
    int n  = t >> 6;                           // 64 threads per node
    int j8 = (t & 63) << 3;
    float a[8] = {0, 0, 0, 0, 0, 0, 0, 0};
#pragma unroll
    for (int k = 0; k < KCH; ++k) {
        int   ch = cidx[n * KCH + k];
        float m  = cmask[n * KCH + k];
        us8 v = *(const us8*)(hb + (size_t)ch * HDIM + j8);
#pragma unroll
        for (int j = 0; j < 8; ++j) a[j] += m * bf2f(v[j]);
    }
    us8 o;
#pragma unroll
    for (int j = 0; j < 8; ++j) o[j] = f2bf(a[j]);
    *(us8*)(outp + (size_t)n * HDIM + j8) = o;
}

// c = sigmoid(i)*tanh(u) + fc ; h = sigmoid(o)*tanh(c) ; also emit h in bf16
template <bool LEAF>
__global__ __launch_bounds__(256) void gate_k(
    const float* __restrict__ iou, const float* __restrict__ fc,
    float* __restrict__ c_new, float* __restrict__ h_new,
    unsigned short* __restrict__ hb_new)
{
    int t  = blockIdx.x * 256 + threadIdx.x;   // NN*HDIM/4 threads
    int n  = t >> 7;
    int j4 = (t & 127) << 2;
    const float* base = iou + (size_t)n * 3 * HDIM;
    float4 iv = *(const float4*)(base + j4);
    float4 ov = *(const float4*)(base + HDIM + j4);
    float4 uv = *(const float4*)(base + 2 * HDIM + j4);
    float4 fcv = LEAF ? make_float4(0, 0, 0, 0)
                      : *(const float4*)(fc + (size_t)n * HDIM + j4);
    float4 cv, hv;
    cv.x = sigf(iv.x) * tanhf(uv.x) + fcv.x;
    cv.y = sigf(iv.y) * tanhf(uv.y) + fcv.y;
    cv.z = sigf(iv.z) * tanhf(uv.z) + fcv.z;
    cv.w = sigf(iv.w) * tanhf(uv.w) + fcv.w;
    hv.x = sigf(ov.x) * tanhf(cv.x);
    hv.y = sigf(ov.y) * tanhf(cv.y);
    hv.z = sigf(ov.z) * tanhf(cv.z);
    hv.w = sigf(ov.w) * tanhf(cv.w);
    *(float4*)(c_new + (size_t)n * HDIM + j4) = cv;
    *(float4*)(h_new + (size_t)n * HDIM + j4) = hv;
    us4 hb;
    hb[0] = f2bf(hv.x); hb[1] = f2bf(hv.y); hb[2] = f2bf(hv.z); hb[3] = f2bf(hv.w);
    *(us4*)(hb_new + (size_t)n * HDIM + j4) = hb;
}

extern "C" void kernel_launch(void* const* d_in, const int* in_sizes, int n_in,
                              void* d_out, int out_size, void* d_ws, size_t ws_size,
                              hipStream_t stream)
{
    const int*   vocab_ix   = (const int*)d_in[0];     // [L,N]
    const int*   child_idx  = (const int*)d_in[1];     // [L,N,K]
    const float* token_mask = (const float*)d_in[2];   // [L,N]
    const float* child_mask = (const float*)d_in[3];   // [L,N,K]
    const float* embed      = (const float*)d_in[4];   // [V,E] fp32
    const float* W_iou      = (const float*)d_in[5];   // [E,3H]
    const float* U_iou      = (const float*)d_in[6];   // [H,3H]
    const float* b_iou      = (const float*)d_in[7];   // [3H]
    const float* W_f        = (const float*)d_in[8];   // [E,H]
    const float* U_f        = (const float*)d_in[9];   // [H,H]
    const float* b_f        = (const float*)d_in[10];  // [H]
    float* out = (float*)d_out;                        // [N,H] level-0 h

    // ---- workspace layout ----
    float* ws  = (float*)d_ws;
    float* iou = ws;                                   // [N,3H] f32
    float* xwf = iou + (size_t)NN * 3 * HDIM;          // [N,H]  f32
    float* fc  = xwf + (size_t)NN * HDIM;              // [N,H]  f32
    float* h0  = fc  + (size_t)NN * HDIM;              // [N,H]  f32
    float* c0  = h0  + (size_t)NN * HDIM;              // [N,H]  f32
    float* c1  = c0  + (size_t)NN * HDIM;              // [N,H]  f32
    unsigned short* us_base = (unsigned short*)(c1 + (size_t)NN * HDIM);
    unsigned short* hb0   = us_base;                            // [N,H] bf16
    unsigned short* hb1   = hb0 + (size_t)NN * HDIM;
    unsigned short* htlb  = hb1 + (size_t)NN * HDIM;            // [N,H] bf16
    unsigned short* WtIOU = htlb + (size_t)NN * HDIM;           // [3H][EPAD]
    unsigned short* UtIOU = WtIOU + (size_t)3 * HDIM * EPAD;    // [3H][H]
    unsigned short* WtF   = UtIOU + (size_t)3 * HDIM * HDIM;    // [H][EPAD]
    unsigned short* UtF   = WtF + (size_t)HDIM * EPAD;          // [H][H]

    dim3 blk(256);

    // ---- convert + transpose weights to bf16 [N][K] ----
    wconv_k<<<dim3(3 * HDIM * EPAD / 256), blk, 0, stream>>>(W_iou, WtIOU, EDIM, EPAD, 3 * HDIM);
    wconv_k<<<dim3(3 * HDIM * HDIM / 256), blk, 0, stream>>>(U_iou, UtIOU, HDIM, HDIM, 3 * HDIM);
    wconv_k<<<dim3(HDIM * EPAD / 256),     blk, 0, stream>>>(W_f,   WtF,   EDIM, EPAD, HDIM);
    wconv_k<<<dim3(HDIM * HDIM / 256),     blk, 0, stream>>>(U_f,   UtF,   HDIM, HDIM, HDIM);

    float*          hbuf[2] = { h0,  out };
    float*          cbuf[2] = { c0,  c1  };
    unsigned short* bbuf[2] = { hb0, hb1 };

    const int gate_blocks = NN * HDIM / 4 / 256;   // 4096
    const int htl_blocks  = NN * HDIM / 8 / 256;   // 2048

    for (int l = LVLS - 1; l >= 0; --l) {
        const int t = (LVLS - 1 - l) & 1;
        float*          h_new  = hbuf[t];
        float*          c_new  = cbuf[t];
        unsigned short* hb_new = bbuf[t];
        float*          c_prev = cbuf[t ^ 1];
        unsigned short* hb_prev = bbuf[t ^ 1];
        const int*   vix = vocab_ix   + (size_t)l * NN;
        const float* tm  = token_mask + (size_t)l * NN;
        const int*   cix = child_idx  + (size_t)l * NN * KCH;
        const float* cm  = child_mask + (size_t)l * NN * KCH;
        const bool leaf = (l == LVLS - 1);

        // iou = (embed[vix]*tm) @ W_iou + b_iou       [8192 x (300->320) x 1536]
        mgemm_k<1, 1, 1><<<dim3(3 * HDIM / BN, NN / BM), blk, 0, stream>>>(
            embed, nullptr, vix, tm, WtIOU, b_iou, iou,
            nullptr, nullptr, nullptr, nullptr, nullptr,
            NN, EPAD, EDIM, 3 * HDIM);

        if (!leaf) {
            // xwf = (embed[vix]*tm) @ W_f             [8192 x 320 x 512]
            mgemm_k<1, 1, 0><<<dim3(HDIM / BN, NN / BM), blk, 0, stream>>>(
                embed, nullptr, vix, tm, WtF, nullptr, xwf,
                nullptr, nullptr, nullptr, nullptr, nullptr,
                NN, EPAD, EDIM, HDIM);

            // h_tilde(bf16) = sum_k mask * h_prev[cidx]
            htilde_k<<<dim3(htl_blocks), blk, 0, stream>>>(hb_prev, cix, cm, htlb);

            // iou += h_tilde @ U_iou                  [8192 x 512 x 1536]
            mgemm_k<0, 0, 2><<<dim3(3 * HDIM / BN, NN / BM), blk, 0, stream>>>(
                nullptr, htlb, nullptr, nullptr, UtIOU, nullptr, iou,
                nullptr, nullptr, nullptr, nullptr, nullptr,
                NN, HDIM, HDIM, 3 * HDIM);

            // fc = sum_k sigmoid((mask*h_prev[cidx]) @ U_f + xwf + b_f) * mask * c_prev[cidx]
            mgemm_k<1, 0, 3><<<dim3(HDIM / BN, NN * KCH / BM), blk, 0, stream>>>(
                nullptr, hb_prev, cix, cm, UtF, nullptr, fc,
                xwf, b_f, cix, cm, c_prev,
                NN * KCH, HDIM, HDIM, HDIM);

            gate_k<false><<<dim3(gate_blocks), blk, 0, stream>>>(iou, fc, c_new, h_new, hb_new);
        } else {
            gate_k<true><<<dim3(gate_blocks), blk, 0, stream>>>(iou, nullptr, c_new, h_new, hb_new);
        }
    }
}

// Round 3
// 822.751 us; speedup vs baseline: 5.1590x; 1.2331x over previous
//
#include <hip/hip_runtime.h>
#include <cmath>

// Problem constants: V=50000, E=300, H=512, L=6, N=8192, K=4
#define VSZ  50000
#define EDIM 300
#define EPAD 320      // E padded to multiple of 32
#define HDIM 512
#define LVLS 6
#define NN   8192
#define KCH  4

// MFMA GEMM tile: 128x128 block, BK=32, 4 waves of 64x64 (4x4 grid of 16x16x32 MFMA)
#define BM 128
#define BN 128
#define BK 32

typedef __attribute__((ext_vector_type(8))) short bf16x8;
typedef __attribute__((ext_vector_type(4))) unsigned short us4;
typedef __attribute__((ext_vector_type(4))) float f32x4;

__device__ __forceinline__ float sigf(float x) { return 1.0f / (1.0f + expf(-x)); }

__device__ __forceinline__ unsigned short f2bf(float f) {
    unsigned u = __float_as_uint(f);
    u += 0x7FFF + ((u >> 16) & 1);           // RNE
    return (unsigned short)(u >> 16);
}

// ---- convert embed [V][E] f32 -> [V][EPAD] bf16 (zero-padded) ----
__global__ __launch_bounds__(256) void econv_k(
    const float* __restrict__ in, unsigned short* __restrict__ out)
{
    int t = blockIdx.x * 256 + threadIdx.x;   // V*EPAD total
    int e = t % EPAD;
    int v = t / EPAD;
    out[t] = (e < EDIM) ? f2bf(in[(size_t)v * EDIM + e]) : (unsigned short)0;
}

// ---- transpose+convert weights: out[n][k] = bf16(in[k][n]), zero for k>=Kreal ----
__global__ __launch_bounds__(256) void wconv_k(
    const float* __restrict__ in, unsigned short* __restrict__ out,
    int Kreal, int Ksp, int Nd)
{
    int t = blockIdx.x * 256 + threadIdx.x;   // Nd*Ksp total, k fast
    int k = t % Ksp;
    int n = t / Ksp;
    out[t] = (k < Kreal) ? f2bf(in[(size_t)k * Nd + n]) : (unsigned short)0;
}

// MODEA: 0 = dense A rows (row tile_m+r), 1 = gathered rows via aidx
// EPI  : 0 = C = acc
//        1 = C = acc*rowscale[row] + (col<1536 ? b_iou[col] : b_f[col-1536])
//        2 = C += acc
// A, B are bf16 with row stride Ks (multiple of 32). C has row stride ldc (f32).
// LDS: XOR-swizzled 16B granules; staged with global_load_lds (dest = wavebase+lane*16).
//   LDS chunk c (row=c>>2, slot=c&3) holds global K-chunk kg = slot ^ ((row>>1)&3).
template <int MODEA, int EPI>
__global__ __launch_bounds__(256) void mgemm_k(
    const unsigned short* __restrict__ Ab,
    const int* __restrict__ aidx, const float* __restrict__ rowscale,
    const unsigned short* __restrict__ Bt,
    const float* __restrict__ b_iou, const float* __restrict__ b_f,
    float* __restrict__ C, int ldc, int Ks)
{
    __shared__ __align__(16) unsigned short As[BM * BK];   // 8 KB
    __shared__ __align__(16) unsigned short Bs[BN * BK];   // 8 KB

    const int tid    = threadIdx.x;
    const int tile_m = blockIdx.y * BM;
    const int tile_n = blockIdx.x * BN;
    const int wave   = tid >> 6;
    const int lane   = tid & 63;
    const int quad   = lane >> 4;
    const int mcol   = lane & 15;
    const int wm     = (wave >> 1) * 64;
    const int wn     = (wave & 1) * 64;

    // staging: thread handles chunks c0=tid and c1=tid+256 (identity LDS placement)
    const int r0  = tid >> 2;
    const int kg0 = (tid & 3) ^ ((r0 >> 1) & 3);
    const int cc1 = tid + 256;
    const int r1  = cc1 >> 2;
    const int kg1 = (cc1 & 3) ^ ((r1 >> 1) & 3);

    const int arow0 = MODEA ? aidx[tile_m + r0] : (tile_m + r0);
    const int arow1 = MODEA ? aidx[tile_m + r1] : (tile_m + r1);
    const unsigned short* asrc0 = Ab + (size_t)arow0 * Ks + kg0 * 8;
    const unsigned short* asrc1 = Ab + (size_t)arow1 * Ks + kg1 * 8;
    const unsigned short* bsrc0 = Bt + (size_t)(tile_n + r0) * Ks + kg0 * 8;
    const unsigned short* bsrc1 = Bt + (size_t)(tile_n + r1) * Ks + kg1 * 8;

    // wave-uniform LDS destinations (ushort offsets; 1 chunk = 8 ushorts)
    __attribute__((address_space(3))) unsigned int* ldsA0 =
        (__attribute__((address_space(3))) unsigned int*)(As + wave * 512);
    __attribute__((address_space(3))) unsigned int* ldsA1 =
        (__attribute__((address_space(3))) unsigned int*)(As + 2048 + wave * 512);
    __attribute__((address_space(3))) unsigned int* ldsB0 =
        (__attribute__((address_space(3))) unsigned int*)(Bs + wave * 512);
    __attribute__((address_space(3))) unsigned int* ldsB1 =
        (__attribute__((address_space(3))) unsigned int*)(Bs + 2048 + wave * 512);

    f32x4 acc[4][4] = {};

    for (int k0 = 0; k0 < Ks; k0 += BK) {
        __builtin_amdgcn_global_load_lds(
            (const __attribute__((address_space(1))) unsigned int*)(asrc0 + k0), ldsA0, 16, 0, 0);
        __builtin_amdgcn_global_load_lds(
            (const __attribute__((address_space(1))) unsigned int*)(asrc1 + k0), ldsA1, 16, 0, 0);
        __builtin_amdgcn_global_load_lds(
            (const __attribute__((address_space(1))) unsigned int*)(bsrc0 + k0), ldsB0, 16, 0, 0);
        __builtin_amdgcn_global_load_lds(
            (const __attribute__((address_space(1))) unsigned int*)(bsrc1 + k0), ldsB1, 16, 0, 0);
        __syncthreads();

        bf16x8 afr[4], bfr[4];
#pragma unroll
        for (int mt = 0; mt < 4; ++mt) {
            int rw = wm + mt * 16 + mcol;
            int p  = rw * 4 + (quad ^ ((rw >> 1) & 3));
            afr[mt] = *(const bf16x8*)(As + p * 8);
        }
#pragma unroll
        for (int nt = 0; nt < 4; ++nt) {
            int rw = wn + nt * 16 + mcol;
            int p  = rw * 4 + (quad ^ ((rw >> 1) & 3));
            bfr[nt] = *(const bf16x8*)(Bs + p * 8);
        }
#pragma unroll
        for (int mt = 0; mt < 4; ++mt)
#pragma unroll
            for (int nt = 0; nt < 4; ++nt)
                acc[mt][nt] = __builtin_amdgcn_mfma_f32_16x16x32_bf16(
                    afr[mt], bfr[nt], acc[mt][nt], 0, 0, 0);
        __syncthreads();
    }

    // epilogue
#pragma unroll
    for (int mt = 0; mt < 4; ++mt) {
        const int rb = tile_m + wm + mt * 16 + quad * 4;
        float4 ts = make_float4(1.f, 1.f, 1.f, 1.f);
        if (EPI == 1) ts = *(const float4*)&rowscale[rb];
        const float tsv[4] = {ts.x, ts.y, ts.z, ts.w};
#pragma unroll
        for (int nt = 0; nt < 4; ++nt) {
            const int col = tile_n + wn + nt * 16 + mcol;
            float bv = 0.0f;
            if (EPI == 1) bv = (col < 3 * HDIM) ? b_iou[col] : b_f[col - 3 * HDIM];
#pragma unroll
            for (int r = 0; r < 4; ++r) {
                size_t o = (size_t)(rb + r) * ldc + col;
                float v = acc[mt][nt][r];
                if (EPI == 1) v = v * tsv[r] + bv;
                if (EPI == 2) C[o] += v;
                else          C[o] = v;
            }
        }
    }
}

// h_tilde (bf16) = sum_k cmask * h_prev_bf16[cidx]
__global__ __launch_bounds__(256) void htilde_k(
    const unsigned short* __restrict__ hb, const int* __restrict__ cidx,
    const float* __restrict__ cmask, unsigned short* __restrict__ outp)
{
    typedef __attribute__((ext_vector_type(8))) unsigned short us8;
    int t  = blockIdx.x * 256 + threadIdx.x;   // NN*HDIM/8 threads
    int n  = t >> 6;
    int j8 = (t & 63) << 3;
    float a[8] = {0, 0, 0, 0, 0, 0, 0, 0};
#pragma unroll
    for (int k = 0; k < KCH; ++k) {
        int   ch = cidx[n * KCH + k];
        float m  = cmask[n * KCH + k];
        us8 v = *(const us8*)(hb + (size_t)ch * HDIM + j8);
#pragma unroll
        for (int j = 0; j < 8; ++j)
            a[j] += m * __uint_as_float(((unsigned)v[j]) << 16);
    }
    us8 o;
#pragma unroll
    for (int j = 0; j < 8; ++j) o[j] = f2bf(a[j]);
    *(us8*)(outp + (size_t)n * HDIM + j8) = o;
}

// fused fc + gates (non-leaf):
//   fc_j  = sum_k sigmoid(xwfb_j + m_k*hU[c_k,j]) * m_k * c_prev[c_k,j]
//   c = sigmoid(i)*tanh(u) + fc ; h = sigmoid(o)*tanh(c)
// ioux row layout: [i(512) | o(512) | u(512) | xwf+b_f(512)], stride 2048
__global__ __launch_bounds__(256) void gatefc_k(
    const float* __restrict__ ioux, const float* __restrict__ hU,
    const int* __restrict__ cidx, const float* __restrict__ cmask,
    const float* __restrict__ c_prev,
    float* __restrict__ c_new, float* __restrict__ h_new,
    unsigned short* __restrict__ hb_new)
{
    int t  = blockIdx.x * 256 + threadIdx.x;   // NN*HDIM/4 threads
    int n  = t >> 7;
    int j4 = (t & 127) << 2;
    const float* base = ioux + (size_t)n * 4 * HDIM;
    float4 iv = *(const float4*)(base + j4);
    float4 ov = *(const float4*)(base + HDIM + j4);
    float4 uv = *(const float4*)(base + 2 * HDIM + j4);
    float4 xw = *(const float4*)(base + 3 * HDIM + j4);
    int4   ci = *(const int4*)&cidx[n * KCH];
    float4 cm = *(const float4*)&cmask[n * KCH];
    float4 fc = make_float4(0, 0, 0, 0);
    const int   cia[4] = {ci.x, ci.y, ci.z, ci.w};
    const float cma[4] = {cm.x, cm.y, cm.z, cm.w};
#pragma unroll
    for (int k = 0; k < KCH; ++k) {
        const float m = cma[k];
        const float4 hu = *(const float4*)(hU + (size_t)cia[k] * HDIM + j4);
        const float4 cp = *(const float4*)(c_prev + (size_t)cia[k] * HDIM + j4);
        fc.x += sigf(xw.x + m * hu.x) * m * cp.x;
        fc.y += sigf(xw.y + m * hu.y) * m * cp.y;
        fc.z += sigf(xw.z + m * hu.z) * m * cp.z;
        fc.w += sigf(xw.w + m * hu.w) * m * cp.w;
    }
    float4 cv, hv;
    cv.x = sigf(iv.x) * tanhf(uv.x) + fc.x;
    cv.y = sigf(iv.y) * tanhf(uv.y) + fc.y;
    cv.z = sigf(iv.z) * tanhf(uv.z) + fc.z;
    cv.w = sigf(iv.w) * tanhf(uv.w) + fc.w;
    hv.x = sigf(ov.x) * tanhf(cv.x);
    hv.y = sigf(ov.y) * tanhf(cv.y);
    hv.z = sigf(ov.z) * tanhf(cv.z);
    hv.w = sigf(ov.w) * tanhf(cv.w);
    *(float4*)(c_new + (size_t)n * HDIM + j4) = cv;
    *(float4*)(h_new + (size_t)n * HDIM + j4) = hv;
    us4 hb;
    hb[0] = f2bf(hv.x); hb[1] = f2bf(hv.y); hb[2] = f2bf(hv.z); hb[3] = f2bf(hv.w);
    *(us4*)(hb_new + (size_t)n * HDIM + j4) = hb;
}

// leaf: fc = 0
__global__ __launch_bounds__(256) void gateleaf_k(
    const float* __restrict__ ioux,
    float* __restrict__ c_new, float* __restrict__ h_new,
    unsigned short* __restrict__ hb_new)
{
    int t  = blockIdx.x * 256 + threadIdx.x;
    int n  = t >> 7;
    int j4 = (t & 127) << 2;
    const float* base = ioux + (size_t)n * 4 * HDIM;
    float4 iv = *(const float4*)(base + j4);
    float4 ov = *(const float4*)(base + HDIM + j4);
    float4 uv = *(const float4*)(base + 2 * HDIM + j4);
    float4 cv, hv;
    cv.x = sigf(iv.x) * tanhf(uv.x);
    cv.y = sigf(iv.y) * tanhf(uv.y);
    cv.z = sigf(iv.z) * tanhf(uv.z);
    cv.w = sigf(iv.w) * tanhf(uv.w);
    hv.x = sigf(ov.x) * tanhf(cv.x);
    hv.y = sigf(ov.y) * tanhf(cv.y);
    hv.z = sigf(ov.z) * tanhf(cv.z);
    hv.w = sigf(ov.w) * tanhf(cv.w);
    *(float4*)(c_new + (size_t)n * HDIM + j4) = cv;
    *(float4*)(h_new + (size_t)n * HDIM + j4) = hv;
    us4 hb;
    hb[0] = f2bf(hv.x); hb[1] = f2bf(hv.y); hb[2] = f2bf(hv.z); hb[3] = f2bf(hv.w);
    *(us4*)(hb_new + (size_t)n * HDIM + j4) = hb;
}

extern "C" void kernel_launch(void* const* d_in, const int* in_sizes, int n_in,
                              void* d_out, int out_size, void* d_ws, size_t ws_size,
                              hipStream_t stream)
{
    const int*   vocab_ix   = (const int*)d_in[0];     // [L,N]
    const int*   child_idx  = (const int*)d_in[1];     // [L,N,K]
    const float* token_mask = (const float*)d_in[2];   // [L,N]
    const float* child_mask = (const float*)d_in[3];   // [L,N,K]
    const float* embed      = (const float*)d_in[4];   // [V,E] f32
    const float* W_iou      = (const float*)d_in[5];   // [E,3H]
    const float* U_iou      = (const float*)d_in[6];   // [H,3H]
    const float* b_iou      = (const float*)d_in[7];   // [3H]
    const float* W_f        = (const float*)d_in[8];   // [E,H]
    const float* U_f        = (const float*)d_in[9];   // [H,H]
    const float* b_f        = (const float*)d_in[10];  // [H]
    float* out = (float*)d_out;                        // [N,H] level-0 h

    // ---- workspace layout (~195 MB) ----
    float* ws   = (float*)d_ws;
    float* ioux = ws;                                  // [N,4H] f32: i|o|u|xwf+bf
    float* hU   = ioux + (size_t)NN * 4 * HDIM;        // [N,H] f32
    float* h0   = hU   + (size_t)NN * HDIM;
    float* c0   = h0   + (size_t)NN * HDIM;
    float* c1   = c0   + (size_t)NN * HDIM;
    unsigned short* usb   = (unsigned short*)(c1 + (size_t)NN * HDIM);
    unsigned short* hb0   = usb;                                // [N,H] bf16
    unsigned short* hb1   = hb0 + (size_t)NN * HDIM;
    unsigned short* htlb  = hb1 + (size_t)NN * HDIM;
    unsigned short* embB  = htlb + (size_t)NN * HDIM;           // [V,EPAD]
    unsigned short* WtALL = embB + (size_t)VSZ * EPAD;          // [4H,EPAD]: W_iou^T | W_f^T
    unsigned short* UtIOU = WtALL + (size_t)4 * HDIM * EPAD;    // [3H,H]
    unsigned short* UtF   = UtIOU + (size_t)3 * HDIM * HDIM;    // [H,H]

    dim3 blk(256);

    // ---- one-time converts (every launch; ws is re-poisoned) ----
    econv_k<<<dim3(VSZ * EPAD / 256), blk, 0, stream>>>(embed, embB);
    wconv_k<<<dim3(3 * HDIM * EPAD / 256), blk, 0, stream>>>(W_iou, WtALL, EDIM, EPAD, 3 * HDIM);
    wconv_k<<<dim3(HDIM * EPAD / 256),     blk, 0, stream>>>(W_f,   WtALL + (size_t)3 * HDIM * EPAD, EDIM, EPAD, HDIM);
    wconv_k<<<dim3(3 * HDIM * HDIM / 256), blk, 0, stream>>>(U_iou, UtIOU, HDIM, HDIM, 3 * HDIM);
    wconv_k<<<dim3(HDIM * HDIM / 256),     blk, 0, stream>>>(U_f,   UtF,   HDIM, HDIM, HDIM);

    float*          hbuf[2] = { h0,  out };
    float*          cbuf[2] = { c0,  c1  };
    unsigned short* bbuf[2] = { hb0, hb1 };

    const int gate_blocks = NN * HDIM / 4 / 256;   // 4096
    const int htl_blocks  = NN * HDIM / 8 / 256;   // 2048

    for (int l = LVLS - 1; l >= 0; --l) {
        const int t = (LVLS - 1 - l) & 1;
        float*          h_new   = hbuf[t];
        float*          c_new   = cbuf[t];
        unsigned short* hb_new  = bbuf[t];
        float*          c_prev  = cbuf[t ^ 1];
        unsigned short* hb_prev = bbuf[t ^ 1];
        const int*   vix = vocab_ix   + (size_t)l * NN;
        const float* tm  = token_mask + (size_t)l * NN;
        const int*   cix = child_idx  + (size_t)l * NN * KCH;
        const float* cm  = child_mask + (size_t)l * NN * KCH;
        const bool leaf = (l == LVLS - 1);

        // [iou | xwf+b_f] = (embed[vix]) @ [W_iou|W_f] * tm_row + bias   [8192 x 320 x 2048]
        // leaf: only the iou 1536 cols are needed
        mgemm_k<1, 1><<<dim3(leaf ? 12 : 16, NN / BM), blk, 0, stream>>>(
            embB, vix, tm, WtALL, b_iou, b_f, ioux, 4 * HDIM, EPAD);

        if (!leaf) {
            // h_tilde(bf16) = sum_k mask * h_prev[cidx]
            htilde_k<<<dim3(htl_blocks), blk, 0, stream>>>(hb_prev, cix, cm, htlb);

            // iou += h_tilde @ U_iou     [8192 x 512 x 1536] into cols 0..1535 of ioux
            mgemm_k<0, 2><<<dim3(12, NN / BM), blk, 0, stream>>>(
                htlb, nullptr, nullptr, UtIOU, nullptr, nullptr, ioux, 4 * HDIM, HDIM);

            // hU = h_prev @ U_f          [8192 x 512 x 512]
            mgemm_k<0, 0><<<dim3(4, NN / BM), blk, 0, stream>>>(
                hb_prev, nullptr, nullptr, UtF, nullptr, nullptr, hU, HDIM, HDIM);

            // fused fc + gates
            gatefc_k<<<dim3(gate_blocks), blk, 0, stream>>>(
                ioux, hU, cix, cm, c_prev, c_new, h_new, hb_new);
        } else {
            gateleaf_k<<<dim3(gate_blocks), blk, 0, stream>>>(ioux, c_new, h_new, hb_new);
        }
    }
}

// Round 4
// 686.260 us; speedup vs baseline: 6.1851x; 1.1989x over previous
//
#include <hip/hip_runtime.h>
#include <cmath>

// Problem constants: V=50000, E=300, H=512, L=6, N=8192, K=4
#define VSZ  50000
#define EDIM 300
#define EPAD 320      // E padded to multiple of 32
#define HDIM 512
#define LVLS 6
#define NN   8192
#define KCH  4

// MFMA GEMM tile: 128x128 block, BK=32, 4 waves of 64x64 (4x4 grid of 16x16x32 MFMA)
#define BM 128
#define BN 128
#define BK 32

typedef __attribute__((ext_vector_type(8))) short bf16x8;
typedef __attribute__((ext_vector_type(8))) unsigned short us8;
typedef __attribute__((ext_vector_type(4))) float f32x4;

__device__ __forceinline__ float sigf(float x) { return 1.0f / (1.0f + expf(-x)); }

__device__ __forceinline__ unsigned short f2bf(float f) {
    unsigned u = __float_as_uint(f);
    u += 0x7FFF + ((u >> 16) & 1);           // RNE
    return (unsigned short)(u >> 16);
}
__device__ __forceinline__ float bf2f(unsigned short h) {
    return __uint_as_float(((unsigned)h) << 16);
}

// ---- convert embed [V][E] f32 -> [V][EPAD] bf16 (zero-padded) ----
__global__ __launch_bounds__(256) void econv_k(
    const float* __restrict__ in, unsigned short* __restrict__ out)
{
    int t = blockIdx.x * 256 + threadIdx.x;   // V*EPAD total
    int e = t % EPAD;
    int v = t / EPAD;
    out[t] = (e < EDIM) ? f2bf(in[(size_t)v * EDIM + e]) : (unsigned short)0;
}

// ---- transpose+convert weights: out[n][k] = bf16(in[k][n]), zero for k>=Kreal ----
__global__ __launch_bounds__(256) void wconv_k(
    const float* __restrict__ in, unsigned short* __restrict__ out,
    int Kreal, int Ksp, int Nd)
{
    int t = blockIdx.x * 256 + threadIdx.x;   // Nd*Ksp total, k fast
    int k = t % Ksp;
    int n = t / Ksp;
    out[t] = (k < Kreal) ? f2bf(in[(size_t)k * Nd + n]) : (unsigned short)0;
}

// MODEA: 0 = dense A rows, 1 = gathered rows via aidx
// EPI  : 0 = C = bf16(acc)
//        1 = C = bf16(acc*rowscale[row] + (col<1536 ? b_iou[col] : b_f[col-1536]))
// Each block processes NCHUNK consecutive N-tiles (A re-reads stay L1/L2-hot).
// LDS: XOR-swizzled 16B granules, staged with global_load_lds (wave-uniform dest).
template <int MODEA, int EPI, int NCHUNK>
__global__ __launch_bounds__(256) void mgemm_k(
    const unsigned short* __restrict__ Ab,
    const int* __restrict__ aidx, const float* __restrict__ rowscale,
    const unsigned short* __restrict__ Bt,
    const float* __restrict__ b_iou, const float* __restrict__ b_f,
    unsigned short* __restrict__ C, int ldc, int Ks)
{
    __shared__ __align__(16) unsigned short As[BM * BK];   // 8 KB
    __shared__ __align__(16) unsigned short Bs[BN * BK];   // 8 KB

    const int tid    = threadIdx.x;
    const int tile_m = blockIdx.y * BM;
    const int wave   = tid >> 6;
    const int lane   = tid & 63;
    const int quad   = lane >> 4;
    const int mcol   = lane & 15;
    const int wm     = (wave >> 1) * 64;
    const int wn     = (wave & 1) * 64;

    // staging: thread handles chunks c0=tid, c1=tid+256 (identity LDS placement)
    const int r0  = tid >> 2;
    const int kg0 = (tid & 3) ^ ((r0 >> 1) & 3);
    const int cc1 = tid + 256;
    const int r1  = cc1 >> 2;
    const int kg1 = (cc1 & 3) ^ ((r1 >> 1) & 3);

    const int arow0 = MODEA ? aidx[tile_m + r0] : (tile_m + r0);
    const int arow1 = MODEA ? aidx[tile_m + r1] : (tile_m + r1);
    const unsigned short* asrc0 = Ab + (size_t)arow0 * Ks + kg0 * 8;
    const unsigned short* asrc1 = Ab + (size_t)arow1 * Ks + kg1 * 8;

    __attribute__((address_space(3))) unsigned int* ldsA0 =
        (__attribute__((address_space(3))) unsigned int*)(As + wave * 512);
    __attribute__((address_space(3))) unsigned int* ldsA1 =
        (__attribute__((address_space(3))) unsigned int*)(As + 2048 + wave * 512);
    __attribute__((address_space(3))) unsigned int* ldsB0 =
        (__attribute__((address_space(3))) unsigned int*)(Bs + wave * 512);
    __attribute__((address_space(3))) unsigned int* ldsB1 =
        (__attribute__((address_space(3))) unsigned int*)(Bs + 2048 + wave * 512);

    for (int nc = 0; nc < NCHUNK; ++nc) {
        const int tile_n = (blockIdx.x * NCHUNK + nc) * BN;
        const unsigned short* bsrc0 = Bt + (size_t)(tile_n + r0) * Ks + kg0 * 8;
        const unsigned short* bsrc1 = Bt + (size_t)(tile_n + r1) * Ks + kg1 * 8;

        f32x4 acc[4][4] = {};

        for (int k0 = 0; k0 < Ks; k0 += BK) {
            __builtin_amdgcn_global_load_lds(
                (const __attribute__((address_space(1))) unsigned int*)(asrc0 + k0), ldsA0, 16, 0, 0);
            __builtin_amdgcn_global_load_lds(
                (const __attribute__((address_space(1))) unsigned int*)(asrc1 + k0), ldsA1, 16, 0, 0);
            __builtin_amdgcn_global_load_lds(
                (const __attribute__((address_space(1))) unsigned int*)(bsrc0 + k0), ldsB0, 16, 0, 0);
            __builtin_amdgcn_global_load_lds(
                (const __attribute__((address_space(1))) unsigned int*)(bsrc1 + k0), ldsB1, 16, 0, 0);
            __syncthreads();

            bf16x8 afr[4], bfr[4];
#pragma unroll
            for (int mt = 0; mt < 4; ++mt) {
                int rw = wm + mt * 16 + mcol;
                int p  = rw * 4 + (quad ^ ((rw >> 1) & 3));
                afr[mt] = *(const bf16x8*)(As + p * 8);
            }
#pragma unroll
            for (int nt = 0; nt < 4; ++nt) {
                int rw = wn + nt * 16 + mcol;
                int p  = rw * 4 + (quad ^ ((rw >> 1) & 3));
                bfr[nt] = *(const bf16x8*)(Bs + p * 8);
            }
#pragma unroll
            for (int mt = 0; mt < 4; ++mt)
#pragma unroll
                for (int nt = 0; nt < 4; ++nt)
                    acc[mt][nt] = __builtin_amdgcn_mfma_f32_16x16x32_bf16(
                        afr[mt], bfr[nt], acc[mt][nt], 0, 0, 0);
            __syncthreads();
        }

        // epilogue: bf16 store
#pragma unroll
        for (int mt = 0; mt < 4; ++mt) {
            const int rb = tile_m + wm + mt * 16 + quad * 4;
            float4 ts = make_float4(1.f, 1.f, 1.f, 1.f);
            if (EPI == 1) ts = *(const float4*)&rowscale[rb];
            const float tsv[4] = {ts.x, ts.y, ts.z, ts.w};
#pragma unroll
            for (int nt = 0; nt < 4; ++nt) {
                const int col = tile_n + wn + nt * 16 + mcol;
                float bv = 0.0f;
                if (EPI == 1) bv = (col < 3 * HDIM) ? b_iou[col] : b_f[col - 3 * HDIM];
#pragma unroll
                for (int r = 0; r < 4; ++r) {
                    size_t o = (size_t)(rb + r) * ldc + col;
                    float v = acc[mt][nt][r];
                    if (EPI == 1) v = v * tsv[r] + bv;
                    C[o] = f2bf(v);
                }
            }
        }
    }
}

// fused child-sum + fc + gates (non-leaf).
// iouxW row: bf16 [i|o|u|xwf+bf] (2048). Z row: bf16 [h@U_iou (1536) | h@U_f (512)].
//   ia = i + sum_k m_k * Zi[c_k] ; (same o,u) ; fc = sum_k sigf(xw + m_k*Zf[c_k]) * m_k * c_prev[c_k]
//   c = sigf(ia)*tanh(ua) + fc ; h = sigf(oa)*tanh(c)
// LAST: write h f32 to h_out only; else write c_new f32 + hb_new bf16.
template <bool LAST>
__global__ __launch_bounds__(256) void gatefc_k(
    const unsigned short* __restrict__ iouxW, const unsigned short* __restrict__ Z,
    const int* __restrict__ cidx, const float* __restrict__ cmask,
    const float* __restrict__ c_prev,
    float* __restrict__ c_new, unsigned short* __restrict__ hb_new,
    float* __restrict__ h_out)
{
    int t  = blockIdx.x * 256 + threadIdx.x;   // NN*HDIM/8 threads
    int n  = t >> 6;
    int j8 = (t & 63) << 3;
    const unsigned short* xr = iouxW + (size_t)n * 4 * HDIM + j8;
    us8 xi = *(const us8*)xr;
    us8 xo = *(const us8*)(xr + HDIM);
    us8 xu = *(const us8*)(xr + 2 * HDIM);
    us8 xf = *(const us8*)(xr + 3 * HDIM);
    float ia[8], oa[8], ua[8], xw[8], fc[8];
#pragma unroll
    for (int j = 0; j < 8; ++j) {
        ia[j] = bf2f(xi[j]); oa[j] = bf2f(xo[j]);
        ua[j] = bf2f(xu[j]); xw[j] = bf2f(xf[j]);
        fc[j] = 0.0f;
    }
    int4   ci = *(const int4*)&cidx[n * KCH];
    float4 cm = *(const float4*)&cmask[n * KCH];
    const int   cia[4] = {ci.x, ci.y, ci.z, ci.w};
    const float cma[4] = {cm.x, cm.y, cm.z, cm.w};
#pragma unroll
    for (int k = 0; k < KCH; ++k) {
        const float m = cma[k];
        const unsigned short* zr = Z + (size_t)cia[k] * 4 * HDIM + j8;
        us8 zi = *(const us8*)zr;
        us8 zo = *(const us8*)(zr + HDIM);
        us8 zu = *(const us8*)(zr + 2 * HDIM);
        us8 zf = *(const us8*)(zr + 3 * HDIM);
        const float* cpr = c_prev + (size_t)cia[k] * HDIM + j8;
        float4 ca = *(const float4*)cpr;
        float4 cb = *(const float4*)(cpr + 4);
        const float cp[8] = {ca.x, ca.y, ca.z, ca.w, cb.x, cb.y, cb.z, cb.w};
#pragma unroll
        for (int j = 0; j < 8; ++j) {
            ia[j] += m * bf2f(zi[j]);
            oa[j] += m * bf2f(zo[j]);
            ua[j] += m * bf2f(zu[j]);
            fc[j] += sigf(xw[j] + m * bf2f(zf[j])) * m * cp[j];
        }
    }
    float cv[8], hv[8];
#pragma unroll
    for (int j = 0; j < 8; ++j) {
        cv[j] = sigf(ia[j]) * tanhf(ua[j]) + fc[j];
        hv[j] = sigf(oa[j]) * tanhf(cv[j]);
    }
    if (LAST) {
        float4 h0 = make_float4(hv[0], hv[1], hv[2], hv[3]);
        float4 h1 = make_float4(hv[4], hv[5], hv[6], hv[7]);
        *(float4*)(h_out + (size_t)n * HDIM + j8)     = h0;
        *(float4*)(h_out + (size_t)n * HDIM + j8 + 4) = h1;
    } else {
        float4 c0v = make_float4(cv[0], cv[1], cv[2], cv[3]);
        float4 c1v = make_float4(cv[4], cv[5], cv[6], cv[7]);
        *(float4*)(c_new + (size_t)n * HDIM + j8)     = c0v;
        *(float4*)(c_new + (size_t)n * HDIM + j8 + 4) = c1v;
        us8 hb;
#pragma unroll
        for (int j = 0; j < 8; ++j) hb[j] = f2bf(hv[j]);
        *(us8*)(hb_new + (size_t)n * HDIM + j8) = hb;
    }
}

// leaf: fc = 0, no children
__global__ __launch_bounds__(256) void gateleaf_k(
    const unsigned short* __restrict__ iouxW,
    float* __restrict__ c_new, unsigned short* __restrict__ hb_new)
{
    int t  = blockIdx.x * 256 + threadIdx.x;
    int n  = t >> 6;
    int j8 = (t & 63) << 3;
    const unsigned short* xr = iouxW + (size_t)n * 4 * HDIM + j8;
    us8 xi = *(const us8*)xr;
    us8 xo = *(const us8*)(xr + HDIM);
    us8 xu = *(const us8*)(xr + 2 * HDIM);
    float cv[8], hv[8];
#pragma unroll
    for (int j = 0; j < 8; ++j) {
        cv[j] = sigf(bf2f(xi[j])) * tanhf(bf2f(xu[j]));
        hv[j] = sigf(bf2f(xo[j])) * tanhf(cv[j]);
    }
    float4 c0v = make_float4(cv[0], cv[1], cv[2], cv[3]);
    float4 c1v = make_float4(cv[4], cv[5], cv[6], cv[7]);
    *(float4*)(c_new + (size_t)n * HDIM + j8)     = c0v;
    *(float4*)(c_new + (size_t)n * HDIM + j8 + 4) = c1v;
    us8 hb;
#pragma unroll
    for (int j = 0; j < 8; ++j) hb[j] = f2bf(hv[j]);
    *(us8*)(hb_new + (size_t)n * HDIM + j8) = hb;
}

extern "C" void kernel_launch(void* const* d_in, const int* in_sizes, int n_in,
                              void* d_out, int out_size, void* d_ws, size_t ws_size,
                              hipStream_t stream)
{
    const int*   vocab_ix   = (const int*)d_in[0];     // [L,N]
    const int*   child_idx  = (const int*)d_in[1];     // [L,N,K]
    const float* token_mask = (const float*)d_in[2];   // [L,N]
    const float* child_mask = (const float*)d_in[3];   // [L,N,K]
    const float* embed      = (const float*)d_in[4];   // [V,E] f32
    const float* W_iou      = (const float*)d_in[5];   // [E,3H]
    const float* U_iou      = (const float*)d_in[6];   // [H,3H]
    const float* b_iou      = (const float*)d_in[7];   // [3H]
    const float* W_f        = (const float*)d_in[8];   // [E,H]
    const float* U_f        = (const float*)d_in[9];   // [H,H]
    const float* b_f        = (const float*)d_in[10];  // [H]
    float* out = (float*)d_out;                        // [N,H] level-0 h

    // ---- workspace layout (~220 MB; ws is 256 MiB) ----
    float* ws = (float*)d_ws;
    float* c0 = ws;                                    // [N,H] f32
    float* c1 = c0 + (size_t)NN * HDIM;                // [N,H] f32
    unsigned short* usb   = (unsigned short*)(c1 + (size_t)NN * HDIM);
    unsigned short* hb0   = usb;                                // [N,H] bf16
    unsigned short* hb1   = hb0 + (size_t)NN * HDIM;            // [N,H] bf16
    unsigned short* iouxW = hb1 + (size_t)NN * HDIM;            // [3N,4H] bf16 (3-level batch)
    unsigned short* Z     = iouxW + (size_t)3 * NN * 4 * HDIM;  // [N,4H] bf16
    unsigned short* embB  = Z + (size_t)NN * 4 * HDIM;          // [V,EPAD] bf16
    unsigned short* WtALL = embB + (size_t)VSZ * EPAD;          // [4H,EPAD] bf16
    unsigned short* UtALL = WtALL + (size_t)4 * HDIM * EPAD;    // [4H,H] bf16

    dim3 blk(256);

    // ---- converts (every launch; ws is re-poisoned) ----
    econv_k<<<dim3(VSZ * EPAD / 256), blk, 0, stream>>>(embed, embB);
    wconv_k<<<dim3(3 * HDIM * EPAD / 256), blk, 0, stream>>>(W_iou, WtALL, EDIM, EPAD, 3 * HDIM);
    wconv_k<<<dim3(HDIM * EPAD / 256),     blk, 0, stream>>>(W_f, WtALL + (size_t)3 * HDIM * EPAD, EDIM, EPAD, HDIM);
    wconv_k<<<dim3(3 * HDIM * HDIM / 256), blk, 0, stream>>>(U_iou, UtALL, HDIM, HDIM, 3 * HDIM);
    wconv_k<<<dim3(HDIM * HDIM / 256),     blk, 0, stream>>>(U_f, UtALL + (size_t)3 * HDIM * HDIM, HDIM, HDIM, HDIM);

    unsigned short* bbuf[2] = { hb0, hb1 };
    float*          cbuf[2] = { c0,  c1  };

    const int ew_blocks = NN * HDIM / 8 / 256;   // 2048

    // Batch A: levels 3..5 (rows l-3), before the recurrence.
    mgemm_k<1, 1, 4><<<dim3(4, 3 * NN / BM), blk, 0, stream>>>(
        embB, vocab_ix + (size_t)3 * NN, token_mask + (size_t)3 * NN,
        WtALL, b_iou, b_f, iouxW, 4 * HDIM, EPAD);

    for (int l = LVLS - 1; l >= 0; --l) {
        const int p = (LVLS - 1 - l);            // 0..5
        unsigned short* hb_new  = bbuf[p & 1];
        float*          c_new   = cbuf[p & 1];
        unsigned short* hb_prev = bbuf[(p & 1) ^ 1];
        float*          c_prev  = cbuf[(p & 1) ^ 1];
        const int*   cix = child_idx  + (size_t)l * NN * KCH;
        const float* cm  = child_mask + (size_t)l * NN * KCH;
        const unsigned short* ix_l =
            iouxW + (size_t)((l >= 3) ? (l - 3) : l) * NN * 4 * HDIM;

        if (l == LVLS - 1) {
            gateleaf_k<<<dim3(ew_blocks), blk, 0, stream>>>(ix_l, c_new, hb_new);
        } else {
            // Z = h_prev @ [U_iou | U_f]        [8192 x 512 x 2048]
            mgemm_k<0, 0, 2><<<dim3(8, NN / BM), blk, 0, stream>>>(
                hb_prev, nullptr, nullptr, UtALL, nullptr, nullptr, Z, 4 * HDIM, HDIM);

            if (l == 0) {
                gatefc_k<true><<<dim3(ew_blocks), blk, 0, stream>>>(
                    ix_l, Z, cix, cm, c_prev, nullptr, nullptr, out);
            } else {
                gatefc_k<false><<<dim3(ew_blocks), blk, 0, stream>>>(
                    ix_l, Z, cix, cm, c_prev, c_new, hb_new, nullptr);
            }
        }

        // After level 3 is consumed, overwrite iouxW with batch B (levels 0..2).
        if (l == 3) {
            mgemm_k<1, 1, 4><<<dim3(4, 3 * NN / BM), blk, 0, stream>>>(
                embB, vocab_ix, token_mask,
                WtALL, b_iou, b_f, iouxW, 4 * HDIM, EPAD);
        }
    }
}